// Round 6
// baseline (3036.916 us; speedup 1.0000x reference)
//
#include <hip/hip_runtime.h>
#include <cstdint>

// ---------------------------------------------------------------------------
// ATSS post-processor v4: SINGLE full-data pass (histogram + static-threshold
// compact collect), exact threshold from histogram, guarded fallback rescan,
// fused filter+sort+decode+NMS per image.
//
static constexpr int NI   = 8;
static constexpr int CC   = 80;
static constexpr int HH   = 160;
static constexpr int WW   = 160;
static constexpr int LL   = HH * WW;     // 25600
static constexpr int PRE_K  = 1000;
static constexpr int POST_K = 100;
static constexpr int HSIZE  = 2048;      // top-13-bit score histogram
static constexpr int CPCH   = 16;        // classes per scan block
static constexpr int NCH    = 5;         // 5 * 16 = 80
static constexpr int LPB    = 1024;      // locations per scan block
static constexpr int LBLK   = 25;        // 25600 / 1024
static constexpr int BPI    = NCH * LBLK;   // 125 scan blocks per image
static constexpr int CAPS   = 98304;     // static candidate cap per image
static constexpr int CAP2   = 4096;      // exact-filtered cap per image
static constexpr float PRE_T = 0.05f;
static constexpr float NMS_T = 0.6f;
static constexpr float BSTAT = 0.55f;    // static collect bound (fast path)
static constexpr float CLIPV = 4.135166556742356f;   // log(1000/16)
static constexpr float IMGM1 = 1279.0f;

__device__ __forceinline__ float sigm(float x) { return 1.0f / (1.0f + expf(-x)); }

// ---------------------------------------------------------------------------
// K1: fused scan. Block = (image, 16-class chunk, 1024-location tile).
// Thread: 4 locations; centerness sigmoided ONCE; 16 class values each.
// Builds per-image 2048-bucket histogram of score bits AND appends all
// candidates with score >= BSTAT to the compact static list.
__global__ __launch_bounds__(256) void k_scan(const float* __restrict__ cls,
                                              const float* __restrict__ ctr,
                                              uint32_t* __restrict__ ghist,
                                              uint32_t* __restrict__ cntS,
                                              unsigned long long* __restrict__ candS) {
    __shared__ uint32_t h[4][HSIZE];
    const int t = threadIdx.x;
    for (int i = t; i < 4 * HSIZE; i += 256) (&h[0][0])[i] = 0u;
    __syncthreads();
    const int blk = blockIdx.x;
    const int n = blk / BPI, rem = blk % BPI, ch = rem / LBLK, lb = rem % LBLK;
    const int l0 = lb * LPB + t * 4;
    const uint32_t bstat = __float_as_uint(BSTAT);
    const float4 cr = *(const float4*)&ctr[(size_t)n * LL + l0];
    const float cv[4] = { sigm(cr.x), sigm(cr.y), sigm(cr.z), sigm(cr.w) };
    uint32_t* hw = h[t >> 6];
    const float* base = cls + ((size_t)n * CC + ch * CPCH) * LL + l0;
#pragma unroll 1
    for (int cc0 = 0; cc0 < CPCH; cc0 += 4) {
        // 4 independent named loads (keep them all in flight)
        const float4 x0 = *(const float4*)&base[(size_t)(cc0 + 0) * LL];
        const float4 x1 = *(const float4*)&base[(size_t)(cc0 + 1) * LL];
        const float4 x2 = *(const float4*)&base[(size_t)(cc0 + 2) * LL];
        const float4 x3 = *(const float4*)&base[(size_t)(cc0 + 3) * LL];
        const float4 xs[4] = { x0, x1, x2, x3 };
#pragma unroll
        for (int u = 0; u < 4; ++u) {
            const int c = ch * CPCH + cc0 + u;
            const float pv[4] = { sigm(xs[u].x), sigm(xs[u].y), sigm(xs[u].z), sigm(xs[u].w) };
#pragma unroll
            for (int k = 0; k < 4; ++k) {
                if (pv[k] > PRE_T) {
                    const uint32_t bits = __float_as_uint(pv[k] * cv[k]);
                    atomicAdd(&hw[bits >> 19], 1u);
                    if (bits >= bstat) {
                        uint32_t pos = atomicAdd(&cntS[n], 1u);
                        if (pos < (uint32_t)CAPS) {
                            uint32_t idx = (uint32_t)(l0 + k) * CC + (uint32_t)c;
                            candS[(size_t)n * CAPS + pos] =
                                ((unsigned long long)bits << 32) | (uint32_t)(~idx);
                        }
                    }
                }
            }
        }
    }
    __syncthreads();
    for (int b = t; b < HSIZE; b += 256) {
        uint32_t s = h[0][b] + h[1][b] + h[2][b] + h[3][b];
        if (s) atomicAdd(&ghist[n * HSIZE + b], s);
    }
}

// ---------------------------------------------------------------------------
// K2: per image: exact threshold bucket T (highest with suffix >= PRE_K) and
// fast-path flag (static list provably contains every key >= T).
__global__ __launch_bounds__(256) void k_thresh(const uint32_t* __restrict__ ghist,
                                                const uint32_t* __restrict__ cntS,
                                                uint32_t* __restrict__ thresh,
                                                uint32_t* __restrict__ flag) {
    __shared__ uint32_t h[HSIZE];
    __shared__ uint32_t chunk[256];
    const int n = blockIdx.x, t = threadIdx.x;
    for (int b = t; b < HSIZE; b += 256) h[b] = ghist[n * HSIZE + b];
    __syncthreads();
    uint32_t s = 0;
    for (int k = 0; k < 8; ++k) s += h[t * 8 + k];
    chunk[t] = s;
    __syncthreads();
    if (t == 0) {
        uint32_t cum = 0;
        int T = 0;
        for (int c = 255; c >= 0; --c) {
            if (cum + chunk[c] >= (uint32_t)PRE_K) {
                for (int b = c * 8 + 7; b >= c * 8; --b) {
                    cum += h[b];
                    if (cum >= (uint32_t)PRE_K) { T = b; break; }
                }
                break;
            }
            cum += chunk[c];
        }
        const uint32_t Tbits = ((uint32_t)T) << 19;
        thresh[n] = Tbits;
        flag[n] = (Tbits >= __float_as_uint(BSTAT) && cntS[n] <= (uint32_t)CAPS) ? 1u : 0u;
    }
}

// ---------------------------------------------------------------------------
// K3: fallback exact rescan (only when the static bound missed; early-exits
// otherwise). Writes exact-filtered keys into cand2.
__global__ __launch_bounds__(256) void k_fallback(const float* __restrict__ cls,
                                                  const float* __restrict__ ctr,
                                                  const uint32_t* __restrict__ thresh,
                                                  const uint32_t* __restrict__ flag,
                                                  uint32_t* __restrict__ cnt2,
                                                  unsigned long long* __restrict__ cand2) {
    const int blk = blockIdx.x;
    const int n = blk / BPI;
    if (flag[n]) return;                       // fast path valid: nothing to do
    const int t = threadIdx.x;
    const int rem = blk % BPI, ch = rem / LBLK, lb = rem % LBLK;
    const int l0 = lb * LPB + t * 4;
    const uint32_t th = thresh[n];
    const float4 cr = *(const float4*)&ctr[(size_t)n * LL + l0];
    const float cv[4] = { sigm(cr.x), sigm(cr.y), sigm(cr.z), sigm(cr.w) };
    const float* base = cls + ((size_t)n * CC + ch * CPCH) * LL + l0;
#pragma unroll 1
    for (int cc = 0; cc < CPCH; ++cc) {
        const float4 x = *(const float4*)&base[(size_t)cc * LL];
        const int c = ch * CPCH + cc;
        const float pv[4] = { sigm(x.x), sigm(x.y), sigm(x.z), sigm(x.w) };
#pragma unroll
        for (int k = 0; k < 4; ++k) {
            if (pv[k] > PRE_T) {
                const uint32_t bits = __float_as_uint(pv[k] * cv[k]);
                if (bits >= th) {
                    uint32_t pos = atomicAdd(&cnt2[n], 1u);
                    if (pos < (uint32_t)CAP2) {
                        uint32_t idx = (uint32_t)(l0 + k) * CC + (uint32_t)c;
                        cand2[(size_t)n * CAP2 + pos] =
                            ((unsigned long long)bits << 32) | (uint32_t)(~idx);
                    }
                }
            }
        }
    }
}

// ---------------------------------------------------------------------------
// K4: per image (1024 threads): filter static list by exact threshold ->
// dense cand2 -> bitonic-sort top-1024 -> decode -> greedy class-aware NMS
// (early exit at 100 kept; suppression only flows forward => exact) -> out.
__global__ __launch_bounds__(1024) void k_sortnms(const unsigned long long* __restrict__ candS,
                                                  const uint32_t* __restrict__ cntS,
                                                  const uint32_t* __restrict__ cnt2g,
                                                  unsigned long long* __restrict__ cand2,
                                                  const uint32_t* __restrict__ thresh,
                                                  const uint32_t* __restrict__ flag,
                                                  const float* __restrict__ reg,
                                                  const float* __restrict__ anch,
                                                  float* __restrict__ out) {
    __shared__ unsigned long long buf[2048];
    __shared__ float bx0[PRE_K], bx1[PRE_K], bx2[PRE_K], bx3[PRE_K];
    __shared__ float ar[PRE_K], scv[PRE_K];
    __shared__ int clsA[PRE_K], sup[PRE_K];
    __shared__ uint32_t s_cnt;
    __shared__ int s_kept;
    __shared__ int s_list[POST_K];
    const int n = blockIdx.x, t = threadIdx.x;
    if (t == 0) { s_cnt = 0; s_kept = 0; }
    __syncthreads();

    // --- gather exact-filtered candidates into cand2[n] ---
    uint32_t M;
    if (flag[n]) {
        const unsigned long long Tkey = ((unsigned long long)thresh[n]) << 32;
        const uint32_t cs = min(cntS[n], (uint32_t)CAPS);
        for (uint32_t gi = t; gi < cs; gi += 1024) {
            unsigned long long key = candS[(size_t)n * CAPS + gi];
            if (key >= Tkey) {
                uint32_t pos = atomicAdd(&s_cnt, 1u);
                if (pos < (uint32_t)CAP2) cand2[(size_t)n * CAP2 + pos] = key;
            }
        }
        __syncthreads();
        M = min(s_cnt, (uint32_t)CAP2);
    } else {
        M = min(cnt2g[n], (uint32_t)CAP2);
    }

    // --- iterated bitonic sort: exact sorted top-1024 of cand2[0..M) ---
    buf[t]        = ((uint32_t)t < M)          ? cand2[(size_t)n * CAP2 + t]        : 0ULL;
    buf[1024 + t] = ((uint32_t)(1024 + t) < M) ? cand2[(size_t)n * CAP2 + 1024 + t] : 0ULL;
    for (uint32_t s = 0;;) {
        for (int k = 2; k <= 2048; k <<= 1) {
            for (int j = k >> 1; j > 0; j >>= 1) {
                __syncthreads();
#pragma unroll
                for (int u = 0; u < 2; ++u) {
                    int i = t + u * 1024;
                    int ixj = i ^ j;
                    if (ixj > i) {
                        unsigned long long a = buf[i], b = buf[ixj];
                        bool desc = ((i & k) == 0);
                        if (desc ? (a < b) : (a > b)) { buf[i] = b; buf[ixj] = a; }
                    }
                }
            }
        }
        __syncthreads();
        s = (s == 0) ? 2048 : s + 1024;
        if (s >= M) break;
        buf[1024 + t] = (s + t < M) ? cand2[(size_t)n * CAP2 + s + t] : 0ULL;
        __syncthreads();
    }

    // --- decode top-1000 ---
    if (t < PRE_K) {
        const unsigned long long key = buf[t];
        if (key == 0ULL) {
            sup[t] = 2; clsA[t] = -1;
            bx0[t] = bx1[t] = bx2[t] = bx3[t] = 0.0f; ar[t] = 0.0f; scv[t] = 0.0f;
        } else {
            const uint32_t bits = (uint32_t)(key >> 32);
            const uint32_t idx = ~(uint32_t)key;
            const int l = (int)(idx / (uint32_t)CC);
            const int c = (int)(idx % (uint32_t)CC);
            const float4 a = *(const float4*)&anch[l * 4];
            const float r0 = reg[((size_t)n * 4 + 0) * LL + l];
            const float r1 = reg[((size_t)n * 4 + 1) * LL + l];
            const float r2 = reg[((size_t)n * 4 + 2) * LL + l];
            const float r3 = reg[((size_t)n * 4 + 3) * LL + l];
            const float w  = a.z - a.x + 1.0f;
            const float h  = a.w - a.y + 1.0f;
            const float cx = a.x + 0.5f * w;
            const float cy = a.y + 0.5f * h;
            const float dx = r0 / 10.0f, dy = r1 / 10.0f;
            const float dw = fminf(r2 / 5.0f, CLIPV), dh = fminf(r3 / 5.0f, CLIPV);
            const float pcx = dx * w + cx, pcy = dy * h + cy;
            const float pw = expf(dw) * w, ph = expf(dh) * h;
            float x1 = pcx - 0.5f * (pw - 1.0f);
            float y1 = pcy - 0.5f * (ph - 1.0f);
            float x2 = pcx + 0.5f * (pw - 1.0f);
            float y2 = pcy + 0.5f * (ph - 1.0f);
            x1 = fminf(fmaxf(x1, 0.0f), IMGM1);
            y1 = fminf(fmaxf(y1, 0.0f), IMGM1);
            x2 = fminf(fmaxf(x2, 0.0f), IMGM1);
            y2 = fminf(fmaxf(y2, 0.0f), IMGM1);
            bx0[t] = x1; bx1[t] = y1; bx2[t] = x2; bx3[t] = y2;
            ar[t] = fmaxf(x2 - x1, 0.0f) * fmaxf(y2 - y1, 0.0f);
            scv[t] = sqrtf(__uint_as_float(bits));
            clsA[t] = c + 1;
            sup[t] = 0;
        }
    }
    __syncthreads();

    // --- greedy class-aware NMS ---
    for (int i = 0; i < PRE_K; ++i) {
        if (s_kept >= POST_K) break;               // uniform (read post-sync)
        if (sup[i] == 0) {
            if (t == 0) s_list[s_kept] = i;
            if (t > i && t < PRE_K && sup[t] == 0 && clsA[t] == clsA[i]) {
                const float xx1 = fmaxf(bx0[i], bx0[t]);
                const float yy1 = fmaxf(bx1[i], bx1[t]);
                const float xx2 = fminf(bx2[i], bx2[t]);
                const float yy2 = fminf(bx3[i], bx3[t]);
                const float iw = fmaxf(xx2 - xx1, 0.0f);
                const float ih = fmaxf(yy2 - yy1, 0.0f);
                const float inter = iw * ih;
                const float iou = inter / (ar[i] + ar[t] - inter + 1e-9f);
                if (iou > NMS_T) sup[t] = 1;
            }
            if (t == 0) s_kept = s_kept + 1;
        }
        __syncthreads();
    }
    __syncthreads();

    // --- output ---
    if (t < POST_K) {
        float o0 = 0.f, o1 = 0.f, o2 = 0.f, o3 = 0.f, o4 = 0.f, lab = 0.f;
        if (t < s_kept) {
            const int i = s_list[t];
            o0 = bx0[i]; o1 = bx1[i]; o2 = bx2[i]; o3 = bx3[i];
            o4 = scv[i]; lab = (float)clsA[i];
        }
        float* dets = out + (size_t)(n * POST_K + t) * 5;
        dets[0] = o0; dets[1] = o1; dets[2] = o2; dets[3] = o3; dets[4] = o4;
        out[(size_t)NI * POST_K * 5 + (size_t)n * POST_K + t] = lab;
    }
}

// ---------------------------------------------------------------------------
extern "C" void kernel_launch(void* const* d_in, const int* in_sizes, int n_in,
                              void* d_out, int out_size, void* d_ws, size_t ws_size,
                              hipStream_t stream) {
    const float* reg  = (const float*)d_in[0];
    const float* ctr  = (const float*)d_in[1];
    const float* cls  = (const float*)d_in[2];
    const float* anch = (const float*)d_in[3];
    float* out = (float*)d_out;

    char* ws = (char*)d_ws;
    size_t off = 0;
    uint32_t* ghist = (uint32_t*)(ws + off); off += (size_t)NI * HSIZE * 4;  // 64 KB
    uint32_t* cntS  = (uint32_t*)(ws + off); off += NI * 4;                  // contig: one memset
    uint32_t* cnt2  = (uint32_t*)(ws + off); off += NI * 4;
    const size_t zbytes = off;                                               // zero [ghist|cntS|cnt2]
    uint32_t* thr   = (uint32_t*)(ws + off); off += 64;
    uint32_t* flg   = (uint32_t*)(ws + off); off += 64;
    unsigned long long* candS = (unsigned long long*)(ws + off); off += (size_t)NI * CAPS * 8; // 6.3 MB
    unsigned long long* cand2 = (unsigned long long*)(ws + off); off += (size_t)NI * CAP2 * 8; // 256 KB

    hipMemsetAsync(ghist, 0, zbytes, stream);
    k_scan    <<<NI * BPI, 256, 0, stream>>>(cls, ctr, ghist, cntS, candS);
    k_thresh  <<<NI,       256, 0, stream>>>(ghist, cntS, thr, flg);
    k_fallback<<<NI * BPI, 256, 0, stream>>>(cls, ctr, thr, flg, cnt2, cand2);
    k_sortnms <<<NI,      1024, 0, stream>>>(candS, cntS, cnt2, cand2, thr, flg, reg, anch, out);
}

// Round 7
// 227.739 us; speedup vs baseline: 13.3351x; 13.3351x over previous
//
#include <hip/hip_runtime.h>
#include <cstdint>

// ---------------------------------------------------------------------------
// ATSS post-processor v5: single cheap full-data pass (logit prefilter ->
// block-aggregated compact list), fine histogram over the compact list for
// the exact top-1000 threshold, guarded exact fallback, fused sort+NMS.
//
static constexpr int NI   = 8;
static constexpr int CC   = 80;
static constexpr int LL   = 25600;       // 160*160
static constexpr int PRE_K  = 1000;
static constexpr int POST_K = 100;
static constexpr int HSIZE  = 2048;
static constexpr int CPCH   = 16;        // classes per scan block
static constexpr int NCH    = 5;
static constexpr int LPB    = 1024;      // locations per scan block
static constexpr int LBLK   = 25;        // 25600/1024
static constexpr int BPI    = NCH * LBLK;   // 125 blocks/image
static constexpr int CAPS   = 49152;     // static list cap/image (~29k expected)
static constexpr int CAPFB  = 16384;     // fallback list cap/image
static constexpr int CAP2   = 8192;      // sort-set cap/image
static constexpr int BUFC   = 1024;      // per-block LDS candidate buffer
static constexpr float PRE_T = 0.05f;
static constexpr float NMS_T = 0.6f;
static constexpr float BSTAT = 0.65f;    // static collect bound
static constexpr float XPRE  = 0.619f;   // conservative logit(BSTAT)
static constexpr uint32_t FBASE = 0x3F000000u;  // bits of 0.5f
static constexpr float CLIPV = 4.135166556742356f;
static constexpr float IMGM1 = 1279.0f;

__device__ __forceinline__ float sigm(float x) { return 1.0f / (1.0f + expf(-x)); }

// ---------------------------------------------------------------------------
// K1: cheap full pass. 98.6% of elements: load + one compare. Selected
// (sigm(x)*cv >= BSTAT) appended to per-block LDS buffer; one global
// atomic per block reserves space in candS[n].
__global__ __launch_bounds__(256) void k_scan(const float* __restrict__ cls,
                                              const float* __restrict__ ctr,
                                              uint32_t* __restrict__ cntS,
                                              uint32_t* __restrict__ ovf,
                                              unsigned long long* __restrict__ candS) {
    __shared__ unsigned long long sbuf[BUFC];
    __shared__ uint32_t s_cnt, s_base;
    const int t = threadIdx.x;
    if (t == 0) s_cnt = 0;
    __syncthreads();
    const int blk = blockIdx.x;
    const int n = blk / BPI, rem = blk % BPI, ch = rem / LBLK, lb = rem % LBLK;
    const int l0 = lb * LPB + t * 4;
    const uint32_t bstat = __float_as_uint(BSTAT);
    const float4 cr = *(const float4*)&ctr[(size_t)n * LL + l0];
    const float cv[4] = { sigm(cr.x), sigm(cr.y), sigm(cr.z), sigm(cr.w) };
    const float* base = cls + ((size_t)n * CC + ch * CPCH) * LL + l0;
#pragma unroll 1
    for (int cc0 = 0; cc0 < CPCH; cc0 += 4) {
        const float4 x0 = *(const float4*)&base[(size_t)(cc0 + 0) * LL];
        const float4 x1 = *(const float4*)&base[(size_t)(cc0 + 1) * LL];
        const float4 x2 = *(const float4*)&base[(size_t)(cc0 + 2) * LL];
        const float4 x3 = *(const float4*)&base[(size_t)(cc0 + 3) * LL];
        const float4 xs[4] = { x0, x1, x2, x3 };
#pragma unroll
        for (int u = 0; u < 4; ++u) {
            const float xv[4] = { xs[u].x, xs[u].y, xs[u].z, xs[u].w };
#pragma unroll
            for (int k = 0; k < 4; ++k) {
                if (xv[k] > XPRE) {                    // rare (~1.5%)
                    const float p = sigm(xv[k]);
                    if (p > PRE_T) {
                        const uint32_t bits = __float_as_uint(p * cv[k]);
                        if (bits >= bstat) {
                            uint32_t pos = atomicAdd(&s_cnt, 1u);
                            if (pos < (uint32_t)BUFC) {
                                uint32_t idx = (uint32_t)(l0 + k) * CC
                                             + (uint32_t)(ch * CPCH + cc0 + u);
                                sbuf[pos] = ((unsigned long long)bits << 32)
                                          | (uint32_t)(~idx);
                            }
                        }
                    }
                }
            }
        }
    }
    __syncthreads();
    if (t == 0) {
        s_base = atomicAdd(&cntS[n], s_cnt);
        if (s_cnt > (uint32_t)BUFC || s_base + s_cnt > (uint32_t)CAPS)
            atomicOr(&ovf[n], 1u);
    }
    __syncthreads();
    const uint32_t wr = min(s_cnt, (uint32_t)BUFC);
    const uint32_t b = s_base;
    if (b < (uint32_t)CAPS) {
        const uint32_t w = min(wr, (uint32_t)CAPS - b);
        for (uint32_t i = t; i < w; i += 256)
            candS[(size_t)n * CAPS + b + i] = sbuf[i];
    }
}

// ---------------------------------------------------------------------------
// K2: fine histogram over the compact list (bucket width 2^12 bits-units).
__global__ __launch_bounds__(256) void k_hist2(const unsigned long long* __restrict__ candS,
                                               const uint32_t* __restrict__ cntS,
                                               uint32_t* __restrict__ ghist2) {
    __shared__ uint32_t h[HSIZE];
    const int t = threadIdx.x;
    const int n = blockIdx.x >> 3, sub = blockIdx.x & 7;
    for (int i = t; i < HSIZE; i += 256) h[i] = 0u;
    __syncthreads();
    const uint32_t cnt = min(cntS[n], (uint32_t)CAPS);
    for (uint32_t i = (uint32_t)(sub * 256 + t); i < cnt; i += 2048) {
        const uint32_t bits = (uint32_t)(candS[(size_t)n * CAPS + i] >> 32);
        const uint32_t idx = min(2047u, (bits - FBASE) >> 12);
        atomicAdd(&h[idx], 1u);
    }
    __syncthreads();
    for (int b = t; b < HSIZE; b += 256)
        if (h[b]) atomicAdd(&ghist2[n * HSIZE + b], h[b]);
}

// ---------------------------------------------------------------------------
// K3: fine threshold + fast-path validity flag.
__global__ __launch_bounds__(256) void k_thresh2(const uint32_t* __restrict__ ghist2,
                                                 const uint32_t* __restrict__ cntS,
                                                 const uint32_t* __restrict__ ovf,
                                                 uint32_t* __restrict__ thr2,
                                                 uint32_t* __restrict__ listlen,
                                                 uint32_t* __restrict__ flag) {
    __shared__ uint32_t h[HSIZE];
    __shared__ uint32_t chunk[256];
    const int n = blockIdx.x, t = threadIdx.x;
    for (int b = t; b < HSIZE; b += 256) h[b] = ghist2[n * HSIZE + b];
    __syncthreads();
    uint32_t s = 0;
    for (int k = 0; k < 8; ++k) s += h[t * 8 + k];
    chunk[t] = s;
    __syncthreads();
    if (t == 0) {
        uint32_t cum = 0, nsel = 0;
        int T2 = -1;
        for (int c = 255; c >= 0 && T2 < 0; --c) {
            if (cum + chunk[c] >= (uint32_t)PRE_K) {
                for (int b = c * 8 + 7; b >= c * 8; --b) {
                    cum += h[b];
                    if (cum >= (uint32_t)PRE_K) { T2 = b; nsel = cum; break; }
                }
            } else cum += chunk[c];
        }
        const uint32_t tb = FBASE + ((uint32_t)max(T2, 0) << 12);
        thr2[n] = tb;
        listlen[n] = min(cntS[n], (uint32_t)CAPS);
        flag[n] = (T2 >= 0 && tb >= __float_as_uint(BSTAT) && !ovf[n] &&
                   nsel <= (uint32_t)CAP2) ? 1u : 0u;
    }
}

// ---------------------------------------------------------------------------
// K4 (guarded, normally no-op): full-pass coarse histogram for bad images.
__global__ __launch_bounds__(256) void k_fbhist(const float* __restrict__ cls,
                                                const float* __restrict__ ctr,
                                                const uint32_t* __restrict__ flag,
                                                uint32_t* __restrict__ ghistC) {
    const int blk = blockIdx.x;
    const int n = blk / BPI;
    if (flag[n]) return;
    __shared__ uint32_t h[4][HSIZE];
    const int t = threadIdx.x;
    for (int i = t; i < 4 * HSIZE; i += 256) (&h[0][0])[i] = 0u;
    __syncthreads();
    const int rem = blk % BPI, ch = rem / LBLK, lb = rem % LBLK;
    const int l0 = lb * LPB + t * 4;
    const float4 cr = *(const float4*)&ctr[(size_t)n * LL + l0];
    const float cv[4] = { sigm(cr.x), sigm(cr.y), sigm(cr.z), sigm(cr.w) };
    uint32_t* hw = h[t >> 6];
    const float* base = cls + ((size_t)n * CC + ch * CPCH) * LL + l0;
#pragma unroll 1
    for (int cc = 0; cc < CPCH; ++cc) {
        const float4 x = *(const float4*)&base[(size_t)cc * LL];
        const float pv[4] = { sigm(x.x), sigm(x.y), sigm(x.z), sigm(x.w) };
#pragma unroll
        for (int k = 0; k < 4; ++k)
            if (pv[k] > PRE_T)
                atomicAdd(&hw[__float_as_uint(pv[k] * cv[k]) >> 19], 1u);
    }
    __syncthreads();
    for (int b = t; b < HSIZE; b += 256) {
        const uint32_t s = h[0][b] + h[1][b] + h[2][b] + h[3][b];
        if (s) atomicAdd(&ghistC[n * HSIZE + b], s);
    }
}

// K5 (guarded): coarse threshold for bad images (overwrites thr2).
__global__ __launch_bounds__(256) void k_fbthresh(const uint32_t* __restrict__ ghistC,
                                                  const uint32_t* __restrict__ flag,
                                                  uint32_t* __restrict__ thr2) {
    const int n = blockIdx.x;
    if (flag[n]) return;
    __shared__ uint32_t h[HSIZE];
    __shared__ uint32_t chunk[256];
    const int t = threadIdx.x;
    for (int b = t; b < HSIZE; b += 256) h[b] = ghistC[n * HSIZE + b];
    __syncthreads();
    uint32_t s = 0;
    for (int k = 0; k < 8; ++k) s += h[t * 8 + k];
    chunk[t] = s;
    __syncthreads();
    if (t == 0) {
        uint32_t cum = 0;
        int T = 0;
        for (int c = 255; c >= 0; --c) {
            if (cum + chunk[c] >= (uint32_t)PRE_K) {
                for (int b = c * 8 + 7; b >= c * 8; --b) {
                    cum += h[b];
                    if (cum >= (uint32_t)PRE_K) { T = b; break; }
                }
                break;
            }
            cum += chunk[c];
        }
        thr2[n] = ((uint32_t)T) << 19;
    }
}

// K6 (guarded): exact collect for bad images into candFB.
__global__ __launch_bounds__(256) void k_fbcollect(const float* __restrict__ cls,
                                                   const float* __restrict__ ctr,
                                                   const uint32_t* __restrict__ flag,
                                                   const uint32_t* __restrict__ thr2,
                                                   uint32_t* __restrict__ cntFB,
                                                   unsigned long long* __restrict__ candFB) {
    const int blk = blockIdx.x;
    const int n = blk / BPI;
    if (flag[n]) return;
    const int t = threadIdx.x;
    const int rem = blk % BPI, ch = rem / LBLK, lb = rem % LBLK;
    const int l0 = lb * LPB + t * 4;
    const uint32_t th = thr2[n];
    const float4 cr = *(const float4*)&ctr[(size_t)n * LL + l0];
    const float cv[4] = { sigm(cr.x), sigm(cr.y), sigm(cr.z), sigm(cr.w) };
    const float* base = cls + ((size_t)n * CC + ch * CPCH) * LL + l0;
#pragma unroll 1
    for (int cc = 0; cc < CPCH; ++cc) {
        const float4 x = *(const float4*)&base[(size_t)cc * LL];
        const float pv[4] = { sigm(x.x), sigm(x.y), sigm(x.z), sigm(x.w) };
#pragma unroll
        for (int k = 0; k < 4; ++k) {
            if (pv[k] > PRE_T) {
                const uint32_t bits = __float_as_uint(pv[k] * cv[k]);
                if (bits >= th) {
                    uint32_t pos = atomicAdd(&cntFB[n], 1u);
                    if (pos < (uint32_t)CAPFB) {
                        uint32_t idx = (uint32_t)(l0 + k) * CC + (uint32_t)(ch * CPCH + cc);
                        candFB[(size_t)n * CAPFB + pos] =
                            ((unsigned long long)bits << 32) | (uint32_t)(~idx);
                    }
                }
            }
        }
    }
}

// ---------------------------------------------------------------------------
// K7: per image: gather >= thr2 -> bitonic top-1024 -> decode -> greedy
// class-aware NMS (early exit at 100 kept, exact) -> output.
__global__ __launch_bounds__(1024) void k_sortnms(const unsigned long long* __restrict__ candS,
                                                  const uint32_t* __restrict__ listlen,
                                                  const unsigned long long* __restrict__ candFB,
                                                  const uint32_t* __restrict__ cntFB,
                                                  unsigned long long* __restrict__ cand2,
                                                  const uint32_t* __restrict__ thr2,
                                                  const uint32_t* __restrict__ flag,
                                                  const float* __restrict__ reg,
                                                  const float* __restrict__ anch,
                                                  float* __restrict__ out) {
    __shared__ unsigned long long buf[2048];
    __shared__ float bx0[PRE_K], bx1[PRE_K], bx2[PRE_K], bx3[PRE_K];
    __shared__ float ar[PRE_K], scv[PRE_K];
    __shared__ int clsA[PRE_K], sup[PRE_K];
    __shared__ uint32_t s_cnt;
    __shared__ int s_kept;
    __shared__ int s_list[POST_K];
    const int n = blockIdx.x, t = threadIdx.x;
    if (t == 0) { s_cnt = 0; s_kept = 0; }
    __syncthreads();

    const bool fp = (flag[n] != 0);
    const unsigned long long* src = fp ? (candS + (size_t)n * CAPS)
                                       : (candFB + (size_t)n * CAPFB);
    const uint32_t len = fp ? listlen[n] : min(cntFB[n], (uint32_t)CAPFB);
    const unsigned long long Tkey = ((unsigned long long)thr2[n]) << 32;
    for (uint32_t gi = t; gi < len; gi += 1024) {
        const unsigned long long key = src[gi];
        if (key >= Tkey) {
            uint32_t pos = atomicAdd(&s_cnt, 1u);
            if (pos < (uint32_t)CAP2) cand2[(size_t)n * CAP2 + pos] = key;
        }
    }
    __syncthreads();
    const uint32_t M = min(s_cnt, (uint32_t)CAP2);

    // iterated bitonic: exact sorted top-1024
    buf[t]        = ((uint32_t)t < M)          ? cand2[(size_t)n * CAP2 + t]        : 0ULL;
    buf[1024 + t] = ((uint32_t)(1024 + t) < M) ? cand2[(size_t)n * CAP2 + 1024 + t] : 0ULL;
    for (uint32_t s = 0;;) {
        for (int k = 2; k <= 2048; k <<= 1) {
            for (int j = k >> 1; j > 0; j >>= 1) {
                __syncthreads();
#pragma unroll
                for (int u = 0; u < 2; ++u) {
                    const int i = t + u * 1024;
                    const int ixj = i ^ j;
                    if (ixj > i) {
                        const unsigned long long a = buf[i], b = buf[ixj];
                        const bool desc = ((i & k) == 0);
                        if (desc ? (a < b) : (a > b)) { buf[i] = b; buf[ixj] = a; }
                    }
                }
            }
        }
        __syncthreads();
        s = (s == 0) ? 2048 : s + 1024;
        if (s >= M) break;
        buf[1024 + t] = (s + t < M) ? cand2[(size_t)n * CAP2 + s + t] : 0ULL;
        __syncthreads();
    }

    // decode top-1000
    if (t < PRE_K) {
        const unsigned long long key = buf[t];
        if (key == 0ULL) {
            sup[t] = 2; clsA[t] = -1;
            bx0[t] = bx1[t] = bx2[t] = bx3[t] = 0.0f; ar[t] = 0.0f; scv[t] = 0.0f;
        } else {
            const uint32_t bits = (uint32_t)(key >> 32);
            const uint32_t idx = ~(uint32_t)key;
            const int l = (int)(idx / (uint32_t)CC);
            const int c = (int)(idx % (uint32_t)CC);
            const float4 a = *(const float4*)&anch[l * 4];
            const float r0 = reg[((size_t)n * 4 + 0) * LL + l];
            const float r1 = reg[((size_t)n * 4 + 1) * LL + l];
            const float r2 = reg[((size_t)n * 4 + 2) * LL + l];
            const float r3 = reg[((size_t)n * 4 + 3) * LL + l];
            const float w  = a.z - a.x + 1.0f;
            const float h  = a.w - a.y + 1.0f;
            const float cx = a.x + 0.5f * w;
            const float cy = a.y + 0.5f * h;
            const float dx = r0 / 10.0f, dy = r1 / 10.0f;
            const float dw = fminf(r2 / 5.0f, CLIPV), dh = fminf(r3 / 5.0f, CLIPV);
            const float pcx = dx * w + cx, pcy = dy * h + cy;
            const float pw = expf(dw) * w, ph = expf(dh) * h;
            float x1 = pcx - 0.5f * (pw - 1.0f);
            float y1 = pcy - 0.5f * (ph - 1.0f);
            float x2 = pcx + 0.5f * (pw - 1.0f);
            float y2 = pcy + 0.5f * (ph - 1.0f);
            x1 = fminf(fmaxf(x1, 0.0f), IMGM1);
            y1 = fminf(fmaxf(y1, 0.0f), IMGM1);
            x2 = fminf(fmaxf(x2, 0.0f), IMGM1);
            y2 = fminf(fmaxf(y2, 0.0f), IMGM1);
            bx0[t] = x1; bx1[t] = y1; bx2[t] = x2; bx3[t] = y2;
            ar[t] = fmaxf(x2 - x1, 0.0f) * fmaxf(y2 - y1, 0.0f);
            scv[t] = sqrtf(__uint_as_float(bits));
            clsA[t] = c + 1;
            sup[t] = 0;
        }
    }
    __syncthreads();

    // greedy class-aware NMS
    for (int i = 0; i < PRE_K; ++i) {
        if (s_kept >= POST_K) break;
        if (sup[i] == 0) {
            if (t == 0) s_list[s_kept] = i;
            if (t > i && t < PRE_K && sup[t] == 0 && clsA[t] == clsA[i]) {
                const float xx1 = fmaxf(bx0[i], bx0[t]);
                const float yy1 = fmaxf(bx1[i], bx1[t]);
                const float xx2 = fminf(bx2[i], bx2[t]);
                const float yy2 = fminf(bx3[i], bx3[t]);
                const float iw = fmaxf(xx2 - xx1, 0.0f);
                const float ih = fmaxf(yy2 - yy1, 0.0f);
                const float inter = iw * ih;
                const float iou = inter / (ar[i] + ar[t] - inter + 1e-9f);
                if (iou > NMS_T) sup[t] = 1;
            }
            if (t == 0) s_kept = s_kept + 1;
        }
        __syncthreads();
    }
    __syncthreads();

    if (t < POST_K) {
        float o0 = 0.f, o1 = 0.f, o2 = 0.f, o3 = 0.f, o4 = 0.f, lab = 0.f;
        if (t < s_kept) {
            const int i = s_list[t];
            o0 = bx0[i]; o1 = bx1[i]; o2 = bx2[i]; o3 = bx3[i];
            o4 = scv[i]; lab = (float)clsA[i];
        }
        float* dets = out + (size_t)(n * POST_K + t) * 5;
        dets[0] = o0; dets[1] = o1; dets[2] = o2; dets[3] = o3; dets[4] = o4;
        out[(size_t)NI * POST_K * 5 + (size_t)n * POST_K + t] = lab;
    }
}

// ---------------------------------------------------------------------------
extern "C" void kernel_launch(void* const* d_in, const int* in_sizes, int n_in,
                              void* d_out, int out_size, void* d_ws, size_t ws_size,
                              hipStream_t stream) {
    const float* reg  = (const float*)d_in[0];
    const float* ctr  = (const float*)d_in[1];
    const float* cls  = (const float*)d_in[2];
    const float* anch = (const float*)d_in[3];
    float* out = (float*)d_out;

    char* ws = (char*)d_ws;
    size_t off = 0;
    uint32_t* ghist2 = (uint32_t*)(ws + off); off += (size_t)NI * HSIZE * 4;  // 64 KB
    uint32_t* ghistC = (uint32_t*)(ws + off); off += (size_t)NI * HSIZE * 4;  // 64 KB
    uint32_t* cntS   = (uint32_t*)(ws + off); off += 32;
    uint32_t* ovf    = (uint32_t*)(ws + off); off += 32;
    uint32_t* cntFB  = (uint32_t*)(ws + off); off += 32;
    const size_t zbytes = off;                       // zero everything above
    uint32_t* thr2    = (uint32_t*)(ws + off); off += 32;
    uint32_t* listlen = (uint32_t*)(ws + off); off += 32;
    uint32_t* flg     = (uint32_t*)(ws + off); off += 32;
    unsigned long long* candS  = (unsigned long long*)(ws + off); off += (size_t)NI * CAPS * 8;  // 3 MB
    unsigned long long* candFB = (unsigned long long*)(ws + off); off += (size_t)NI * CAPFB * 8; // 1 MB
    unsigned long long* cand2  = (unsigned long long*)(ws + off); off += (size_t)NI * CAP2 * 8;  // 512 KB

    hipMemsetAsync(ghist2, 0, zbytes, stream);
    k_scan     <<<NI * BPI, 256, 0, stream>>>(cls, ctr, cntS, ovf, candS);
    k_hist2    <<<NI * 8,   256, 0, stream>>>(candS, cntS, ghist2);
    k_thresh2  <<<NI,       256, 0, stream>>>(ghist2, cntS, ovf, thr2, listlen, flg);
    k_fbhist   <<<NI * BPI, 256, 0, stream>>>(cls, ctr, flg, ghistC);
    k_fbthresh <<<NI,       256, 0, stream>>>(ghistC, flg, thr2);
    k_fbcollect<<<NI * BPI, 256, 0, stream>>>(cls, ctr, flg, thr2, cntFB, candFB);
    k_sortnms  <<<NI,      1024, 0, stream>>>(candS, listlen, candFB, cntFB, cand2,
                                              thr2, flg, reg, anch, out);
}